// Round 5
// baseline (141.163 us; speedup 1.0000x reference)
//
#include <hip/hip_runtime.h>
#include <hip/hip_bf16.h>

// FourierKANLayer: out[n,o] = bias[o] + sum_{i,b} coeffs[o,i,b] * basis[n,i,b]
// basis = [1, sin(m*pi*x) m=1..32, cos(m*pi*x) m=1..32] per (n,i).
//
// R5 design: bf16 MFMA 32x32x16. Wave = 64 rows x 32 cols x HALF-K (i-split):
// block 256 thr = 4 waves over (i-half, col-half); all waves share 64 rows.
// Each ds_read_b128 B-frag feeds 2 MFMAs (2 row-tiles) -> LDS 75% of MFMA.
// fp32 Chebyshev recurrence (v' = T*v - v_prev, T=2cos(pi*x)), 32 instances
// per lane = 160 VGPR state -> 2 waves/SIMD. Mode-pair unroll (no reg moves).
// K-partials summed via LDS in epilogue. Double-buffered pair staging
// (2 x 32 KB LDS), global_load_lds(16B). Grid 1024, 2 blocks/CU.

typedef __bf16 bf16x8 __attribute__((ext_vector_type(8)));
typedef float  f32x4  __attribute__((ext_vector_type(4)));
typedef float  f32x16 __attribute__((ext_vector_type(16)));

#define PI_F 3.14159265358979323846f

// ---------------------------------------------------------------------------
// Repack coeffs [64][64][65] fp32 -> Bp bf16 in 32x32x16 B-fragment order.
// One thread per input element (coalesced read, scattered 2B write):
//   b==0 -> atomicAdd into bias2sum[o] (pre-zeroed via hipMemsetAsync)
//   else  m=(b-1)&31, sc=(b>=33), frag=(m*8+kc)*2+cc, lane=kq*32+(o&31),
//         t=2*(i&3)+sc;  Bp[frag*512 + lane*8 + t] = bf16(v)
// Bp total: 512 frags * 512 elems * 2 B = 512 KB. bias2sum AFTER it.
// ---------------------------------------------------------------------------
__global__ __launch_bounds__(256) void fkan_repack(
    const float* __restrict__ coeffs, __bf16* __restrict__ Bp,
    float* __restrict__ bias2sum) {
  int gid = blockIdx.x * 256 + threadIdx.x;   // 0 .. 266239
  if (gid >= 64 * 64 * 65) return;
  float v = coeffs[gid];
  int b  = gid % 65;
  int oi = gid / 65;
  int i = oi & 63;
  int o = oi >> 6;
  if (b == 0) {
    atomicAdd(&bias2sum[o], v);
    return;
  }
  int m  = (b - 1) & 31;
  int sc = (b >= 33) ? 1 : 0;
  int kc = i >> 3;
  int kq = (i >> 2) & 1;
  int cc = o >> 5;
  int frag = (m * 8 + kc) * 2 + cc;
  int lane = kq * 32 + (o & 31);
  int t = 2 * (i & 3) + sc;
  Bp[frag * 512 + lane * 8 + t] = (__bf16)v;
}

// ---------------------------------------------------------------------------
// Stage one mode-PAIR (32 KB) into LDS: 256 threads x 16 B x 8 rounds.
// LDS dest is wave-uniform base + lane*16 (global_load_lds constraint).
// ---------------------------------------------------------------------------
__device__ __forceinline__ void stage_pair(const __bf16* __restrict__ Bp,
                                           __bf16* dst, int pair, int wave,
                                           int lane) {
  const char* g = (const char*)Bp + (size_t)pair * 32768 + wave * 1024 + lane * 16;
  char* l = (char*)dst + wave * 1024;
  #pragma unroll
  for (int r = 0; r < 8; ++r) {
    __builtin_amdgcn_global_load_lds(
        (const __attribute__((address_space(1))) void*)(g + r * 4096),
        (__attribute__((address_space(3))) void*)(l + r * 4096), 16, 0, 0);
  }
}

// ---------------------------------------------------------------------------
// Main kernel: 256 threads = 4 waves; block = 64 rows x 64 cols, all-K.
// Wave w: ih = w>>1 (i-half), cw = w&1 (col-half). 64 rows (2 x 32-row
// tiles), 32 cols, K-half = i in [ih*32, ih*32+32).
// Lane: cl=lane&31 (row in tile), kq=lane>>5 (K-quarter of frag).
// Lane instance p = t*16 + kc*4 + e  <->  (row = base+t*32+cl,
//   i = ih*32 + kc*8 + kq*4 + e), kc in [0,4), e in [0,4).
// Per mode: 2 tiles x 4 kc = 8 MFMA, 4 B-frag ds_read_b128 (each feeds 2).
// Epilogue: ih=1 waves push partials through LDS; ih=0 waves add + store.
// ---------------------------------------------------------------------------
__global__ __launch_bounds__(256, 2) void fkan_main(
    const float* __restrict__ x, const __bf16* __restrict__ Bp,
    const float* __restrict__ bias, const float* __restrict__ bias2sum,
    float* __restrict__ out) {
  __shared__ __bf16 Bs[2][16384];   // 2 x 32 KB (one mode-pair each)

  int tid  = threadIdx.x;
  int wave = tid >> 6;
  int lane = tid & 63;
  int kq   = lane >> 5;
  int cl   = lane & 31;
  int ih   = wave >> 1;
  int cw   = wave & 1;
  int rowbase = blockIdx.x * 64;

  // --- init: Chebyshev state for 32 (row,i) instances ----------------------
  // cur = mode 1 = (sin,cos)(pi*x); prev = mode 0 = (0,1); T = 2cos(pi*x).
  float sC[32], cC[32], sP[32], cP[32], Tch[32];
  #pragma unroll
  for (int t = 0; t < 2; ++t) {
    const float* xrow =
        x + (size_t)(rowbase + t * 32 + cl) * 64 + ih * 32 + kq * 4;
    #pragma unroll
    for (int kc = 0; kc < 4; ++kc) {
      f32x4 v = *(const f32x4*)(xrow + kc * 8);
      #pragma unroll
      for (int e = 0; e < 4; ++e) {
        int p = t * 16 + kc * 4 + e;
        float ss, cs;
        __sincosf(PI_F * v[e], &ss, &cs);
        sC[p] = ss;  cC[p] = cs;
        sP[p] = 0.f; cP[p] = 1.f;
        Tch[p] = 2.0f * cs;
      }
    }
  }

  f32x16 acc[2];
  #pragma unroll
  for (int t = 0; t < 2; ++t)
    #pragma unroll
    for (int r = 0; r < 16; ++r) acc[t][r] = 0.f;

  stage_pair(Bp, &Bs[0][0], 0, wave, lane);
  __syncthreads();

  // --- mode-pair loop: pair p covers freqs 2p+1 (cur) and 2p+2 (prev) ------
  for (int p = 0; p < 16; ++p) {
    int buf = p & 1;
    if (p < 15) stage_pair(Bp, &Bs[buf ^ 1][0], p + 1, wave, lane);

    // ---- first mode of pair: A from (sC,cC), B at LDS offset 0
    #pragma unroll
    for (int kc = 0; kc < 4; ++kc) {
      bf16x8 bfr = *(const bf16x8*)(
          &Bs[buf][((ih * 4 + kc) * 2 + cw) * 512 + lane * 8]);
      #pragma unroll
      for (int t = 0; t < 2; ++t) {
        bf16x8 af;
        #pragma unroll
        for (int e = 0; e < 4; ++e) {
          af[2 * e]     = (__bf16)sC[t * 16 + kc * 4 + e];
          af[2 * e + 1] = (__bf16)cC[t * 16 + kc * 4 + e];
        }
        acc[t] = __builtin_amdgcn_mfma_f32_32x32x16_bf16(af, bfr, acc[t],
                                                         0, 0, 0);
      }
    }
    // advance: prev <- mode 2p+2 (one fma per chain, in-place, no moves)
    #pragma unroll
    for (int q = 0; q < 32; ++q) {
      sP[q] = fmaf(Tch[q], sC[q], -sP[q]);
      cP[q] = fmaf(Tch[q], cC[q], -cP[q]);
    }

    // ---- second mode of pair: A from (sP,cP), B at LDS offset 8192
    #pragma unroll
    for (int kc = 0; kc < 4; ++kc) {
      bf16x8 bfr = *(const bf16x8*)(
          &Bs[buf][8192 + ((ih * 4 + kc) * 2 + cw) * 512 + lane * 8]);
      #pragma unroll
      for (int t = 0; t < 2; ++t) {
        bf16x8 af;
        #pragma unroll
        for (int e = 0; e < 4; ++e) {
          af[2 * e]     = (__bf16)sP[t * 16 + kc * 4 + e];
          af[2 * e + 1] = (__bf16)cP[t * 16 + kc * 4 + e];
        }
        acc[t] = __builtin_amdgcn_mfma_f32_32x32x16_bf16(af, bfr, acc[t],
                                                         0, 0, 0);
      }
    }
    // advance: cur <- mode 2p+3
    #pragma unroll
    for (int q = 0; q < 32; ++q) {
      sC[q] = fmaf(Tch[q], sP[q], -sC[q]);
      cC[q] = fmaf(Tch[q], cP[q], -cC[q]);
    }
    __syncthreads();
  }

  // --- epilogue: reduce K-halves across wave pairs via LDS -----------------
  float* Lf = (float*)&Bs[0][0];     // 16 KB scratch (barrier above protects)
  if (ih == 1) {
    #pragma unroll
    for (int t = 0; t < 2; ++t)
      #pragma unroll
      for (int r = 0; r < 16; ++r)
        Lf[cw * 2048 + t * 1024 + r * 64 + lane] = acc[t][r];
  }
  __syncthreads();
  if (ih == 0) {
    int col = cw * 32 + cl;
    float bv = bias[col] + bias2sum[col];
    #pragma unroll
    for (int t = 0; t < 2; ++t) {
      float* orow = out + (size_t)(rowbase + t * 32) * 64;
      #pragma unroll
      for (int r = 0; r < 16; ++r) {
        float sum = acc[t][r] + Lf[cw * 2048 + t * 1024 + r * 64 + lane];
        int ro = (r & 3) + 8 * (r >> 2) + 4 * kq;
        orow[(size_t)ro * 64 + col] = sum + bv;
      }
    }
  }
}

extern "C" void kernel_launch(void* const* d_in, const int* in_sizes, int n_in,
                              void* d_out, int out_size, void* d_ws, size_t ws_size,
                              hipStream_t stream) {
  const float* x      = (const float*)d_in[0];   // [65536, 64]
  const float* coeffs = (const float*)d_in[1];   // [64, 64, 65]
  const float* bias   = (const float*)d_in[2];   // [64]
  float* out = (float*)d_out;

  __bf16* Bp      = (__bf16*)d_ws;               // 512 KB (512 frags * 1 KB)
  float* bias2sum = (float*)((char*)d_ws + 512 * 1024);  // AFTER Bp

  int n_rows = in_sizes[0] / 64;                 // 65536

  hipMemsetAsync(bias2sum, 0, 64 * sizeof(float), stream);
  fkan_repack<<<(64 * 64 * 65 + 255) / 256, 256, 0, stream>>>(coeffs, Bp,
                                                              bias2sum);
  fkan_main<<<n_rows / 64, 256, 0, stream>>>(x, Bp, bias, bias2sum, out);
}